// Round 1
// baseline (346.644 us; speedup 1.0000x reference)
//
#include <hip/hip_runtime.h>

#define BATCH 16384
#define CTX 10
#define MAXC 24
#define EMBED 128

// One wave (64 lanes) per batch row. Each lane owns 2 embedding dims (float2),
// so one wave-wide float2 load fetches exactly one 512B embedding row, fully
// coalesced. Scores reduced with a 6-step shfl_xor butterfly (all 24 at once).
__global__ __launch_bounds__(256) void cbow_hs_kernel(
    const int* __restrict__ ctx_words,   // [B, CTX]
    const int* __restrict__ paths,       // [B, MAXC]
    const int* __restrict__ codes,       // [B, MAXC]
    const int* __restrict__ mask,        // [B, MAXC] (bool -> int32)
    const float* __restrict__ W_in,      // [VOCAB, 128]
    const float* __restrict__ W_internal,// [VOCAB-1, 128]
    float* __restrict__ out)             // [1]
{
    const int lane = threadIdx.x & 63;
    int row = blockIdx.x * 4 + (threadIdx.x >> 6);
    // wave-uniform row index -> SGPR so index loads become scalar loads
    row = __builtin_amdgcn_readfirstlane(row);

    // ---- context mean: each lane accumulates its 2 dims over 10 words ----
    const float2* Win2 = (const float2*)W_in;
    float2 acc = make_float2(0.f, 0.f);
#pragma unroll
    for (int k = 0; k < CTX; ++k) {
        const int w = ctx_words[row * CTX + k];          // scalar load (uniform)
        const float2 e = Win2[(long)w * 64 + lane];      // 512B coalesced
        acc.x += e.x;
        acc.y += e.y;
    }
    const float inv = 1.0f / (float)CTX;
    acc.x *= inv;
    acc.y *= inv;

    // ---- per-lane partial dot products for all 24 path nodes ----
    const float2* Wn2 = (const float2*)W_internal;
    float part[MAXC];
#pragma unroll
    for (int l = 0; l < MAXC; ++l) {
        const int p = paths[row * MAXC + l];             // scalar load (uniform)
        const float2 e = Wn2[(long)p * 64 + lane];       // 512B coalesced
        part[l] = acc.x * e.x + acc.y * e.y;
    }

    // ---- butterfly reduce all 24 partials across the 64-lane wave ----
#pragma unroll
    for (int off = 32; off; off >>= 1) {
#pragma unroll
        for (int l = 0; l < MAXC; ++l)
            part[l] += __shfl_xor(part[l], off, 64);
    }

    // ---- loss: -logsigmoid(sign*score), masked; wave-uniform compute ----
    float total = 0.f;
#pragma unroll
    for (int l = 0; l < MAXC; ++l) {
        const int c = codes[row * MAXC + l];             // scalar (uniform)
        const int m = mask[row * MAXC + l];              // scalar (uniform)
        const float s = part[l];
        const float z = (c != 0) ? s : -s;               // sign*score
        // softplus(-z) = max(-z,0) + log1p(exp(-|z|))
        const float loss = fmaxf(-z, 0.f) + log1pf(expf(-fabsf(z)));
        total += m ? loss : 0.f;
    }

    if (lane == 0)
        atomicAdd(out, total * (1.0f / (float)BATCH));
}

extern "C" void kernel_launch(void* const* d_in, const int* in_sizes, int n_in,
                              void* d_out, int out_size, void* d_ws, size_t ws_size,
                              hipStream_t stream) {
    const int*   ctx_words  = (const int*)d_in[0];
    const int*   paths      = (const int*)d_in[1];
    const int*   codes      = (const int*)d_in[2];
    const int*   mask       = (const int*)d_in[3];
    const float* W_in       = (const float*)d_in[4];
    const float* W_internal = (const float*)d_in[5];
    float* out = (float*)d_out;

    // d_out is re-poisoned (0xAA) before every timed launch -> zero it first.
    hipMemsetAsync(out, 0, sizeof(float), stream);

    // 4 waves per 256-thread block, one row per wave.
    cbow_hs_kernel<<<BATCH / 4, 256, 0, stream>>>(
        ctx_words, paths, codes, mask, W_in, W_internal, out);
}

// Round 3
// 165.880 us; speedup vs baseline: 2.0897x; 2.0897x over previous
//
#include <hip/hip_runtime.h>

#define BATCH 16384
#define CTX 10
#define MAXC 24
#define ROWS_PER_BLOCK 8              // 4 waves * 2 rows per wave
#define GRID_MAIN (BATCH / ROWS_PER_BLOCK)   // 2048 blocks

// Half-wave (32 lanes) per batch row, float4 per lane: 32*16B = one full 512B
// embedding row per half-wave load. One wave handles 2 rows. No global atomics:
// block partial -> d_ws, second kernel reduces.
__global__ __launch_bounds__(256) void cbow_hs_main(
    const int* __restrict__ ctx_words,   // [B, CTX]
    const int* __restrict__ paths,       // [B, MAXC]
    const int* __restrict__ codes,       // [B, MAXC]
    const int* __restrict__ mask,        // [B, MAXC]
    const float* __restrict__ W_in,      // [VOCAB, 128]
    const float* __restrict__ W_internal,// [VOCAB-1, 128]
    float* __restrict__ partials)        // [GRID_MAIN]
{
    const int tid  = threadIdx.x;
    const int lane = tid & 63;
    const int half = lane >> 5;          // which row of the wave's pair
    const int l5   = lane & 31;          // lane within half-wave
    const int wave = tid >> 6;           // 0..3
    const int row  = blockIdx.x * ROWS_PER_BLOCK + wave * 2 + half;

    const float4* Win4 = (const float4*)W_in;        // 32 float4 per emb row
    const float4* Wn4  = (const float4*)W_internal;

    // ---- context mean: each lane owns 4 dims ----
    float4 acc = make_float4(0.f, 0.f, 0.f, 0.f);
#pragma unroll
    for (int k = 0; k < CTX; ++k) {
        const int w = ctx_words[row * CTX + k];       // broadcast within half
        const float4 e = Win4[(long)w * 32 + l5];     // 512B coalesced / half
        acc.x += e.x; acc.y += e.y; acc.z += e.z; acc.w += e.w;
    }
    const float inv = 1.0f / (float)CTX;
    acc.x *= inv; acc.y *= inv; acc.z *= inv; acc.w *= inv;

    // ---- per-lane partial dots for all 24 path nodes ----
    float part[MAXC];
#pragma unroll
    for (int l = 0; l < MAXC; ++l) {
        const int p = paths[row * MAXC + l];
        const float4 e = Wn4[(long)p * 32 + l5];
        part[l] = acc.x * e.x + acc.y * e.y + acc.z * e.z + acc.w * e.w;
    }

    // ---- 5-step butterfly within each 32-lane half (offsets stay in-half) ----
#pragma unroll
    for (int off = 16; off; off >>= 1) {
#pragma unroll
        for (int l = 0; l < MAXC; ++l)
            part[l] += __shfl_xor(part[l], off, 64);
    }

    // ---- masked loss, uniform within half-wave ----
    float total = 0.f;
#pragma unroll
    for (int l = 0; l < MAXC; ++l) {
        const int c = codes[row * MAXC + l];
        const int m = mask[row * MAXC + l];
        const float s = part[l];
        const float z = c ? s : -s;                   // sign*score
        const float loss = fmaxf(-z, 0.f) + log1pf(expf(-fabsf(z)));
        total += m ? loss : 0.f;
    }

    // ---- block reduce via LDS; ONE plain store per block, no atomics ----
    __shared__ float red[ROWS_PER_BLOCK];
    if (l5 == 0) red[wave * 2 + half] = total;
    __syncthreads();
    if (tid == 0) {
        float s = 0.f;
#pragma unroll
        for (int i = 0; i < ROWS_PER_BLOCK; ++i) s += red[i];
        partials[blockIdx.x] = s;
    }
}

__global__ __launch_bounds__(256) void cbow_hs_reduce(
    const float* __restrict__ partials, float* __restrict__ out)
{
    const int tid = threadIdx.x;
    float s = 0.f;
#pragma unroll
    for (int i = 0; i < GRID_MAIN / 256; ++i)         // 8 each
        s += partials[tid + i * 256];
#pragma unroll
    for (int off = 32; off; off >>= 1)
        s += __shfl_xor(s, off, 64);
    __shared__ float red[4];
    if ((tid & 63) == 0) red[tid >> 6] = s;
    __syncthreads();
    if (tid == 0)
        out[0] = (red[0] + red[1] + red[2] + red[3]) * (1.0f / (float)BATCH);
}

extern "C" void kernel_launch(void* const* d_in, const int* in_sizes, int n_in,
                              void* d_out, int out_size, void* d_ws, size_t ws_size,
                              hipStream_t stream) {
    const int*   ctx_words  = (const int*)d_in[0];
    const int*   paths      = (const int*)d_in[1];
    const int*   codes      = (const int*)d_in[2];
    const int*   mask       = (const int*)d_in[3];
    const float* W_in       = (const float*)d_in[4];
    const float* W_internal = (const float*)d_in[5];
    float* out      = (float*)d_out;
    float* partials = (float*)d_ws;   // 2048 floats, fully written before read

    cbow_hs_main<<<GRID_MAIN, 256, 0, stream>>>(
        ctx_words, paths, codes, mask, W_in, W_internal, partials);
    cbow_hs_reduce<<<1, 256, 0, stream>>>(partials, out);
}